// Round 3
// baseline (218.668 us; speedup 1.0000x reference)
//
#include <hip/hip_runtime.h>
#include <hip/hip_bf16.h>
#include <cstdint>

// Problem constants (reference: N=16384, F=1024, H=256)
#define NR 16384
#define NF 1024
#define NH 256

typedef __bf16 bf16x8 __attribute__((ext_vector_type(8)));
typedef float f32x4 __attribute__((ext_vector_type(4)));
typedef unsigned short us8 __attribute__((ext_vector_type(8)));

static __device__ __forceinline__ unsigned short f2bf(float f) {
    unsigned u = __float_as_uint(f);
    u += 0x7FFFu + ((u >> 16) & 1u);   // RNE
    return (unsigned short)(u >> 16);
}

// Fragment-major packed weights (1 KB per cell = 64 lanes x 16 B):
//   Wepk[nb=16][kc=32][lane=q*16+n][e=8] = bf16(We[kc*32+q*8+e][nb*16+n])
//   Wdpk[nb=64][kc= 8][lane=q*16+n][e=8] = bf16(Wd[kc*32+q*8+e][nb*16+n])
// hdr: [0..63] mse cells, [64..127] pair cells, [128] pair ticket,
//      [129] nP (int), [130] nR (int)

// ---------------------------------------------------------------------------
// prep: zero hdr + pack weights. 32 blocks: b<16 We, else Wd.
// ---------------------------------------------------------------------------
__global__ __launch_bounds__(256) void prep_kernel(
    const float* __restrict__ We, const float* __restrict__ Wd,
    unsigned short* __restrict__ Wepk, unsigned short* __restrict__ Wdpk,
    float* __restrict__ hdr) {
    const int b = blockIdx.x, t = threadIdx.x;
    if (b == 0 && t < 192) hdr[t] = 0.f;
    const int lane = t & 63, q = lane >> 4, li = lane & 15, idx = t >> 6;
    if (b < 16) {
        const int nb = b;
#pragma unroll
        for (int p = 0; p < 8; p++) {
            const int kc = idx + 4 * p;                  // 0..31
            us8 v;
#pragma unroll
            for (int e = 0; e < 8; e++)
                v[e] = f2bf(We[(size_t)(kc * 32 + q * 8 + e) * NH + nb * 16 + li]);
            *(us8*)&Wepk[((size_t)(nb * 32 + kc)) * 512 + lane * 8] = v;
        }
    } else {
        const int nb4 = b - 16;                          // 0..15
#pragma unroll
        for (int p = 0; p < 8; p++) {
            const int c = nb4 * 32 + idx + 4 * p;        // 0..511
            const int nb = c >> 3, kc = c & 7;
            us8 v;
#pragma unroll
            for (int e = 0; e < 8; e++)
                v[e] = f2bf(Wd[(size_t)(kc * 32 + q * 8 + e) * NF + nb * 16 + li]);
            *(us8*)&Wdpk[((size_t)(nb * 8 + kc)) * 512 + lane * 8] = v;
        }
    }
}

// ---------------------------------------------------------------------------
// FUSED: grid 512 x 256 thr (4 waves), 32 m-rows/block.
// R1 hypothesis under test: K-split X staging — stage 32x512 halves into a
// 32 KB LDS buffer (was 64 KB monolithic) -> 4 blocks/CU instead of 2.
//  phase 0a: stage X[:, 0:512)  -> LDS bf16, granule^row swizzle (64 chunks)
//  phase 1a: g += X @ We over k in [0,512)
//  phase 0b: restage X[:, 512:1024) into the SAME buffer
//  phase 1b: g += X @ We over k in [512,1024)
//  epilogue: critic c per row -> in-block compaction into cP/cR
//  phase 2: rec = g @ Wd + bd (A = gs LDS, B = Wdpk prefetch); MSE vs X fp32
// Accumulation order identical to the 191.6us baseline -> bitwise-same result.
// ---------------------------------------------------------------------------
__global__ __launch_bounds__(256, 4) void fused_kernel(
    const float* __restrict__ X,
    const unsigned short* __restrict__ Wepk, const unsigned short* __restrict__ Wdpk,
    const float* __restrict__ be, const float* __restrict__ bd,
    const float* __restrict__ Wc, const int* __restrict__ s, const int* __restrict__ pv,
    float* __restrict__ cP, float* __restrict__ cR, float* __restrict__ hdr) {
    __shared__ union {
        unsigned short xa[32 * 512];    // 32 KB: bf16 X half-tile (phases 0/1)
        struct {
            unsigned short gs[32 * 256]; // 16 KB: g tile (phase 2)
            float credu[4][32];
            float msred[4];
        } p2;
    } u;
    const int t = threadIdx.x;
    const int b = blockIdx.x, m0 = b * 32;
    const int w = t >> 6, lane = t & 63, q = lane >> 4, li = lane & 15;
    const int wn = w * 64;    // phase-1 wave n-slice [wn, wn+64)

    // staging geometry (shared by both halves)
    const int sr = t >> 3, scg = t & 7;   // row 0..31, chunk-group 0..7

    // ---------------- phase 0a: stage X k-half 0 into LDS ------------------
    {
        const float* xrow = X + (size_t)(m0 + sr) * NF + scg * 64;
#pragma unroll
        for (int ci = 0; ci < 8; ++ci) {
            float4 lo = *(const float4*)(xrow + ci * 8);
            float4 hi = *(const float4*)(xrow + ci * 8 + 4);
            us8 v;
            v[0] = f2bf(lo.x); v[1] = f2bf(lo.y); v[2] = f2bf(lo.z); v[3] = f2bf(lo.w);
            v[4] = f2bf(hi.x); v[5] = f2bf(hi.y); v[6] = f2bf(hi.z); v[7] = f2bf(hi.w);
            const int chl = scg * 8 + ci;      // local k-chunk 0..63
            *(us8*)&u.xa[sr * 512 + ((chl ^ sr) & 63) * 8] = v;
        }
    }
    __syncthreads();

    // ---------------- phase 1: X @ We (2-deep B prefetch, K-split) ----------
    const unsigned short* Bp[4];
#pragma unroll
    for (int j = 0; j < 4; j++)
        Bp[j] = Wepk + ((size_t)(w * 4 + j) * 32) * 512 + lane * 8;

    us8 fb[2][4];
#pragma unroll
    for (int z = 0; z < 2; ++z)
#pragma unroll
        for (int j = 0; j < 4; j++) fb[z][j] = *(const us8*)(Bp[j] + z * 512);

    f32x4 acc[2][4] = {};

    // ---- half 0: kc 0..15 ----
#pragma unroll
    for (int k2 = 0; k2 < 16; ++k2) {
        const int kc = k2;
        const int cb = kc & 1;
        const int chl = k2 * 4 + q;                       // 0..63
        const int ph0 = (chl ^ li) & 63;
        const int ph1 = (chl ^ (16 + li)) & 63;
        bf16x8 a0 = __builtin_bit_cast(bf16x8, *(const us8*)&u.xa[li * 512 + ph0 * 8]);
        bf16x8 a1 = __builtin_bit_cast(bf16x8, *(const us8*)&u.xa[(16 + li) * 512 + ph1 * 8]);
#pragma unroll
        for (int j = 0; j < 4; j++) {
            bf16x8 bf = __builtin_bit_cast(bf16x8, fb[cb][j]);
            acc[0][j] = __builtin_amdgcn_mfma_f32_16x16x32_bf16(bf, a0, acc[0][j], 0, 0, 0);
            acc[1][j] = __builtin_amdgcn_mfma_f32_16x16x32_bf16(bf, a1, acc[1][j], 0, 0, 0);
        }
        // reload consumed slot with kc+2 (2-deep pipeline, no 3rd generation)
#pragma unroll
        for (int j = 0; j < 4; j++) fb[cb][j] = *(const us8*)(Bp[j] + (kc + 2) * 512);
    }
    __syncthreads();   // all waves done reading xa half 0

    // ---------------- phase 0b: restage k-half 1 into same buffer ----------
    {
        const float* xrow = X + (size_t)(m0 + sr) * NF + 512 + scg * 64;
#pragma unroll
        for (int ci = 0; ci < 8; ++ci) {
            float4 lo = *(const float4*)(xrow + ci * 8);
            float4 hi = *(const float4*)(xrow + ci * 8 + 4);
            us8 v;
            v[0] = f2bf(lo.x); v[1] = f2bf(lo.y); v[2] = f2bf(lo.z); v[3] = f2bf(lo.w);
            v[4] = f2bf(hi.x); v[5] = f2bf(hi.y); v[6] = f2bf(hi.z); v[7] = f2bf(hi.w);
            const int chl = scg * 8 + ci;
            *(us8*)&u.xa[sr * 512 + ((chl ^ sr) & 63) * 8] = v;
        }
    }
    __syncthreads();

    // ---- half 1: kc 16..31 (fb already holds kc=16,17 from half-0 tail) ----
#pragma unroll
    for (int k2 = 0; k2 < 16; ++k2) {
        const int kc = 16 + k2;
        const int cb = kc & 1;
        const int chl = k2 * 4 + q;
        const int ph0 = (chl ^ li) & 63;
        const int ph1 = (chl ^ (16 + li)) & 63;
        bf16x8 a0 = __builtin_bit_cast(bf16x8, *(const us8*)&u.xa[li * 512 + ph0 * 8]);
        bf16x8 a1 = __builtin_bit_cast(bf16x8, *(const us8*)&u.xa[(16 + li) * 512 + ph1 * 8]);
#pragma unroll
        for (int j = 0; j < 4; j++) {
            bf16x8 bf = __builtin_bit_cast(bf16x8, fb[cb][j]);
            acc[0][j] = __builtin_amdgcn_mfma_f32_16x16x32_bf16(bf, a0, acc[0][j], 0, 0, 0);
            acc[1][j] = __builtin_amdgcn_mfma_f32_16x16x32_bf16(bf, a1, acc[1][j], 0, 0, 0);
        }
        if (kc + 2 < 32) {
#pragma unroll
            for (int j = 0; j < 4; j++) fb[cb][j] = *(const us8*)(Bp[j] + (kc + 2) * 512);
        }
    }
    __syncthreads();   // all waves done reading xa; p2 region writable

    // phase-2 B prefetch (global, independent) issued before epilogue
    const unsigned short* Wp = Wdpk + lane * 8;
    us8 gb[2][4];
#pragma unroll
    for (int z = 0; z < 2; ++z)
#pragma unroll
        for (int j = 0; j < 4; j++)
            gb[z][j] = *(const us8*)(Wp + ((size_t)((w * 4 + j) * 8 + z)) * 512);

    // epilogue: g -> swizzled gs + fused critic
#pragma unroll
    for (int i = 0; i < 2; i++) {
        float csum = 0.f;
        const int ml = i * 16 + li;
#pragma unroll
        for (int j = 0; j < 4; j++) {
            const int colb = wn + j * 16 + q * 4;
            float4 be4 = *(const float4*)&be[colb];
            float4 wc4 = *(const float4*)&Wc[colb];
            float v0 = acc[i][j][0] + be4.x;
            float v1 = acc[i][j][1] + be4.y;
            float v2 = acc[i][j][2] + be4.z;
            float v3 = acc[i][j][3] + be4.w;
            csum += v0 * wc4.x + v1 * wc4.y + v2 * wc4.z + v3 * wc4.w;
            ushort4 st = { f2bf(v0), f2bf(v1), f2bf(v2), f2bf(v3) };
            const int phys = (colb >> 3) ^ ml;
            *(ushort4*)&u.p2.gs[ml * 256 + phys * 8 + (q & 1) * 4] = st;
        }
        csum += __shfl_down(csum, 32);
        csum += __shfl_down(csum, 16);
        if (lane < 16) u.p2.credu[w][i * 16 + lane] = csum;
    }
    __syncthreads();   // gs + credu ready

    // in-block compaction of this block's 32 critic values into cP/cR
    if (t < 32) {
        float cs = u.p2.credu[0][t] + u.p2.credu[1][t] +
                   u.p2.credu[2][t] + u.p2.credu[3][t];
        bool pr = (s[m0 + t] == pv[0]);
        unsigned long long mk = __ballot(pr);
        int np = __popcll(mk);
        int baseP = 0, baseR = 0;
        if (t == 0) {
            baseP = atomicAdd((int*)hdr + 129, np);
            baseR = atomicAdd((int*)hdr + 130, 32 - np);
        }
        baseP = __shfl(baseP, 0);
        baseR = __shfl(baseR, 0);
        int offP = __popcll(mk & ((1ull << t) - 1ull));
        int offR = t - offP;
        if (pr) cP[baseP + offP] = cs; else cR[baseR + offR] = cs;
    }

    // ---------------- phase 2: g @ Wd + MSE (no barriers) -------------------
    float lsum = 0.f;
    f32x4 a2[2][4] = {};
#pragma unroll
    for (int it = 0; it < 32; ++it) {
        const int cb = it & 1, pass = it >> 3, kc = it & 7;
        bf16x8 af[2];
#pragma unroll
        for (int i = 0; i < 2; i++) {
            const int ml = i * 16 + li;
            const int phys = (kc * 4 + q) ^ ml;
            af[i] = __builtin_bit_cast(bf16x8, *(const us8*)&u.p2.gs[ml * 256 + phys * 8]);
        }
#pragma unroll
        for (int j = 0; j < 4; j++) {
            bf16x8 bf = __builtin_bit_cast(bf16x8, gb[cb][j]);
            a2[0][j] = __builtin_amdgcn_mfma_f32_16x16x32_bf16(bf, af[0], a2[0][j], 0, 0, 0);
            a2[1][j] = __builtin_amdgcn_mfma_f32_16x16x32_bf16(bf, af[1], a2[1][j], 0, 0, 0);
        }
        if (it + 2 < 32) {
            const int p2i = (it + 2) >> 3, k2 = (it + 2) & 7;
#pragma unroll
            for (int j = 0; j < 4; j++)
                gb[cb][j] = *(const us8*)(Wp + ((size_t)((p2i * 16 + w * 4 + j) * 8 + k2)) * 512);
        }
        if (kc == 7) {   // per-pass epilogue: rec vs X fp32 (L3-warm)
#pragma unroll
            for (int i = 0; i < 2; i++) {
                const size_t rowoff = (size_t)(m0 + i * 16 + li) * NF;
#pragma unroll
                for (int j = 0; j < 4; j++) {
                    const int colb = pass * 256 + wn + j * 16 + q * 4;
                    float4 bd4 = *(const float4*)&bd[colb];
                    float4 xr  = *(const float4*)&X[rowoff + colb];
                    float d0 = a2[i][j][0] + bd4.x - xr.x;
                    float d1 = a2[i][j][1] + bd4.y - xr.y;
                    float d2 = a2[i][j][2] + bd4.z - xr.z;
                    float d3 = a2[i][j][3] + bd4.w - xr.w;
                    lsum += d0 * d0 + d1 * d1 + d2 * d2 + d3 * d3;
                    a2[i][j] = (f32x4){0.f, 0.f, 0.f, 0.f};
                }
            }
        }
    }
#pragma unroll
    for (int o = 32; o; o >>= 1) lsum += __shfl_down(lsum, o);
    if (lane == 0) u.p2.msred[w] = lsum;
    __syncthreads();
    if (t == 0)
        atomicAdd(&hdr[b & 63], u.p2.msred[0] + u.p2.msred[1] +
                                u.p2.msred[2] + u.p2.msred[3]);
}

// ---------------------------------------------------------------------------
// compacted pairwise L1 + fused finalize (last-ticket block writes d_out)
// grid (16 j-chunks x 32 i-chunks of 512)
// ---------------------------------------------------------------------------
__global__ __launch_bounds__(256) void pair_fin_kernel(
    const float* __restrict__ cP, const float* __restrict__ cR,
    float* __restrict__ hdr, float* __restrict__ out) {
    __shared__ float sj[1024];
    __shared__ float red[256];
    __shared__ int win;
    const int nP = ((const int*)hdr)[129];
    const int nR = ((const int*)hdr)[130];
    const int jb = blockIdx.x * 1024;
    int jn = nR - jb; if (jn < 0) jn = 0; if (jn > 1024) jn = 1024;
    float sum = 0.f;
    if (jn > 0 && blockIdx.y * 512 < nP) {
        for (int j = threadIdx.x; j < 1024; j += 256)
            sj[j] = (jb + j < nR) ? cR[jb + j] : 0.f;
        __syncthreads();
        const int a0 = blockIdx.y * 512 + threadIdx.x, a1 = a0 + 256;
        const float ca0 = (a0 < nP) ? cP[a0] : 0.f;
        const float ca1 = (a1 < nP) ? cP[a1] : 0.f;
        float s0 = 0.f, s1 = 0.f;
#pragma unroll 8
        for (int j4 = 0; j4 < 256; j4++) {
            float4 v = *(const float4*)&sj[j4 * 4];
            s0 += fabsf(ca0 - v.x) + fabsf(ca0 - v.y) + fabsf(ca0 - v.z) + fabsf(ca0 - v.w);
            s1 += fabsf(ca1 - v.x) + fabsf(ca1 - v.y) + fabsf(ca1 - v.z) + fabsf(ca1 - v.w);
        }
        float pad = (float)(1024 - jn);
        s0 -= pad * fabsf(ca0);
        s1 -= pad * fabsf(ca1);
        if (a0 >= nP) s0 = 0.f;
        if (a1 >= nP) s1 = 0.f;
        sum = s0 + s1;
#pragma unroll
        for (int o = 32; o; o >>= 1) sum += __shfl_down(sum, o);
        if ((threadIdx.x & 63) == 0 && sum != 0.f)
            atomicAdd(&hdr[64 + ((blockIdx.y * 16 + blockIdx.x) & 63)], sum);
    }
    __threadfence();
    __syncthreads();
    if (threadIdx.x == 0)
        win = (atomicAdd((int*)(hdr + 128), 1) == 16 * 32 - 1) ? 1 : 0;
    __syncthreads();
    if (win) {
        float v = (threadIdx.x < 128) ? atomicAdd(&hdr[threadIdx.x], 0.f) : 0.f;
        red[threadIdx.x] = v;
        __syncthreads();
        if (threadIdx.x == 0) {
            float ms = 0.f, ps = 0.f;
            for (int i = 0; i < 64; i++) { ms += red[i]; ps += red[64 + i]; }
            int np = atomicAdd((int*)(hdr + 129), 0);
            out[0] = ms / (float)((size_t)NR * NF);
            out[1] = (float)NR;
            out[2] = ps / (float)np;
            out[3] = (float)np;
        }
    }
}

extern "C" void kernel_launch(void* const* d_in, const int* in_sizes, int n_in,
                              void* d_out, int out_size, void* d_ws, size_t ws_size,
                              hipStream_t stream) {
    const float* X  = (const float*)d_in[0];
    const float* We = (const float*)d_in[1];
    const float* be = (const float*)d_in[2];
    const float* Wd = (const float*)d_in[3];
    const float* bd = (const float*)d_in[4];
    const float* Wc = (const float*)d_in[5];
    // bc (d_in[6]) omitted: cancels in |c_i - c_j|
    const int*   s  = (const int*)d_in[7];
    const int*   pv = (const int*)d_in[8];

    char* ws = (char*)d_ws;
    float* hdr = (float*)ws;                                     // 192 f
    float* cP  = (float*)(ws + 1024);                            // 64 KB
    float* cR  = (float*)(ws + 1024 + 65536);                    // 64 KB
    unsigned short* Wepk = (unsigned short*)(ws + 1024 + 2 * 65536);  // 512 KB
    unsigned short* Wdpk = Wepk + (size_t)NH * NF;                    // 512 KB

    prep_kernel<<<32, 256, 0, stream>>>(We, Wd, Wepk, Wdpk, hdr);
    fused_kernel<<<512, 256, 0, stream>>>(X, Wepk, Wdpk, be, bd, Wc, s, pv, cP, cR, hdr);
    pair_fin_kernel<<<dim3(16, 32), 256, 0, stream>>>(cP, cR, hdr, (float*)d_out);
}

// Round 4
// 214.407 us; speedup vs baseline: 1.0199x; 1.0199x over previous
//
#include <hip/hip_runtime.h>
#include <hip/hip_bf16.h>
#include <cstdint>

// Problem constants (reference: N=16384, F=1024, H=256)
#define NR 16384
#define NF 1024
#define NH 256

typedef __bf16 bf16x8 __attribute__((ext_vector_type(8)));
typedef float f32x4 __attribute__((ext_vector_type(4)));
typedef unsigned short us8 __attribute__((ext_vector_type(8)));

static __device__ __forceinline__ unsigned short f2bf(float f) {
    unsigned u = __float_as_uint(f);
    u += 0x7FFFu + ((u >> 16) & 1u);   // RNE
    return (unsigned short)(u >> 16);
}

// Fragment-major packed weights (1 KB per cell = 64 lanes x 16 B):
//   Wepk[nb=16][kc=32][lane=q*16+n][e=8] = bf16(We[kc*32+q*8+e][nb*16+n])
//   Wdpk[nb=64][kc= 8][lane=q*16+n][e=8] = bf16(Wd[kc*32+q*8+e][nb*16+n])
// hdr: [0..63] mse cells, [64..127] pair cells, [128] pair ticket,
//      [129] nP (int), [130] nR (int)

// ---------------------------------------------------------------------------
// prep: zero hdr + pack weights. 32 blocks: b<16 We, else Wd.
// ---------------------------------------------------------------------------
__global__ __launch_bounds__(256) void prep_kernel(
    const float* __restrict__ We, const float* __restrict__ Wd,
    unsigned short* __restrict__ Wepk, unsigned short* __restrict__ Wdpk,
    float* __restrict__ hdr) {
    const int b = blockIdx.x, t = threadIdx.x;
    if (b == 0 && t < 192) hdr[t] = 0.f;
    const int lane = t & 63, q = lane >> 4, li = lane & 15, idx = t >> 6;
    if (b < 16) {
        const int nb = b;
#pragma unroll
        for (int p = 0; p < 8; p++) {
            const int kc = idx + 4 * p;                  // 0..31
            us8 v;
#pragma unroll
            for (int e = 0; e < 8; e++)
                v[e] = f2bf(We[(size_t)(kc * 32 + q * 8 + e) * NH + nb * 16 + li]);
            *(us8*)&Wepk[((size_t)(nb * 32 + kc)) * 512 + lane * 8] = v;
        }
    } else {
        const int nb4 = b - 16;                          // 0..15
#pragma unroll
        for (int p = 0; p < 8; p++) {
            const int c = nb4 * 32 + idx + 4 * p;        // 0..511
            const int nb = c >> 3, kc = c & 7;
            us8 v;
#pragma unroll
            for (int e = 0; e < 8; e++)
                v[e] = f2bf(Wd[(size_t)(kc * 32 + q * 8 + e) * NF + nb * 16 + li]);
            *(us8*)&Wdpk[((size_t)(nb * 8 + kc)) * 512 + lane * 8] = v;
        }
    }
}

// ---------------------------------------------------------------------------
// FUSED: grid 1024 x 256 thr (4 waves), 16 m-rows/block, 32 KB LDS.
// R3: grid was 512 blocks = 2 blocks/CU hard ceiling (R3 counters:
// Occupancy 20%, MfmaUtil 7.5%). 16-row blocks double the grid -> 4
// blocks/CU resident. launch_bounds cap REMOVED (R1's (256,4) cap spilled
// ~440 B/thread: WRITE_SIZE 58 MB, VGPR_Count 64).
//  phase 0: stage own X strip (16x1024) -> LDS bf16, granule^row swizzle
//  phase 1: g = X @ We + be (A from LDS, B = Wepk 2-deep prefetch)
//  epilogue: critic c per row -> in-block compaction into cP/cR
//  phase 2: rec = g @ Wd + bd (A = gs LDS, B = Wdpk prefetch); MSE vs X fp32
// Per-row K accumulation order identical to baseline -> same numerics.
// ---------------------------------------------------------------------------
__global__ __launch_bounds__(256) void fused_kernel(
    const float* __restrict__ X,
    const unsigned short* __restrict__ Wepk, const unsigned short* __restrict__ Wdpk,
    const float* __restrict__ be, const float* __restrict__ bd,
    const float* __restrict__ Wc, const int* __restrict__ s, const int* __restrict__ pv,
    float* __restrict__ cP, float* __restrict__ cR, float* __restrict__ hdr) {
    __shared__ union {
        unsigned short xa[16 * 1024];   // 32 KB: bf16 X tile (phases 0/1)
        struct {
            unsigned short gs[16 * 256]; // 8 KB: g tile (phase 2)
            float credu[4][16];
            float msred[4];
        } p2;
    } u;
    const int t = threadIdx.x;
    const int b = blockIdx.x, m0 = b * 16;
    const int w = t >> 6, lane = t & 63, q = lane >> 4, li = lane & 15;
    const int wn = w * 64;    // wave n-slice [wn, wn+64)

    // ---------------- phase 0: stage X tile into LDS (bf16, swizzled) ------
    {
        const int r = t >> 4, cg = t & 15;    // row 0..15, chunk-group 0..15
        const float* xrow = X + (size_t)(m0 + r) * NF + cg * 64;
#pragma unroll
        for (int ci = 0; ci < 8; ++ci) {
            float4 lo = *(const float4*)(xrow + ci * 8);
            float4 hi = *(const float4*)(xrow + ci * 8 + 4);
            us8 v;
            v[0] = f2bf(lo.x); v[1] = f2bf(lo.y); v[2] = f2bf(lo.z); v[3] = f2bf(lo.w);
            v[4] = f2bf(hi.x); v[5] = f2bf(hi.y); v[6] = f2bf(hi.z); v[7] = f2bf(hi.w);
            const int chl = cg * 8 + ci;      // k-chunk 0..127
            *(us8*)&u.xa[r * 1024 + ((chl ^ r) & 127) * 8] = v;
        }
    }
    __syncthreads();

    // ---------------- phase 1: X @ We (2-deep B prefetch, no barriers) ------
    const unsigned short* Bp[4];
#pragma unroll
    for (int j = 0; j < 4; j++)
        Bp[j] = Wepk + ((size_t)(w * 4 + j) * 32) * 512 + lane * 8;

    us8 fb[2][4];
#pragma unroll
    for (int z = 0; z < 2; ++z)
#pragma unroll
        for (int j = 0; j < 4; j++) fb[z][j] = *(const us8*)(Bp[j] + z * 512);

    f32x4 acc[4] = {};
#pragma unroll
    for (int kc = 0; kc < 32; ++kc) {
        const int cb = kc & 1;
        const int chl = kc * 4 + q;                       // 0..127
        const int ph0 = (chl ^ li) & 127;
        bf16x8 a0 = __builtin_bit_cast(bf16x8, *(const us8*)&u.xa[li * 1024 + ph0 * 8]);
#pragma unroll
        for (int j = 0; j < 4; j++) {
            bf16x8 bf = __builtin_bit_cast(bf16x8, fb[cb][j]);
            acc[j] = __builtin_amdgcn_mfma_f32_16x16x32_bf16(bf, a0, acc[j], 0, 0, 0);
        }
        if (kc + 2 < 32) {
#pragma unroll
            for (int j = 0; j < 4; j++) fb[cb][j] = *(const us8*)(Bp[j] + (kc + 2) * 512);
        }
    }
    __syncthreads();   // all waves done reading xa; p2 region writable

    // phase-2 B prefetch (global, independent) issued before epilogue
    const unsigned short* Wp = Wdpk + lane * 8;
    us8 gb[2][4];
#pragma unroll
    for (int z = 0; z < 2; ++z)
#pragma unroll
        for (int j = 0; j < 4; j++)
            gb[z][j] = *(const us8*)(Wp + ((size_t)((w * 4 + j) * 8 + z)) * 512);

    // epilogue: g -> swizzled gs + fused critic (single 16-row m-frag)
    {
        float csum = 0.f;
        const int ml = li;
#pragma unroll
        for (int j = 0; j < 4; j++) {
            const int colb = wn + j * 16 + q * 4;
            float4 be4 = *(const float4*)&be[colb];
            float4 wc4 = *(const float4*)&Wc[colb];
            float v0 = acc[j][0] + be4.x;
            float v1 = acc[j][1] + be4.y;
            float v2 = acc[j][2] + be4.z;
            float v3 = acc[j][3] + be4.w;
            csum += v0 * wc4.x + v1 * wc4.y + v2 * wc4.z + v3 * wc4.w;
            ushort4 st = { f2bf(v0), f2bf(v1), f2bf(v2), f2bf(v3) };
            const int phys = (colb >> 3) ^ ml;
            *(ushort4*)&u.p2.gs[ml * 256 + phys * 8 + (q & 1) * 4] = st;
        }
        csum += __shfl_down(csum, 32);
        csum += __shfl_down(csum, 16);
        if (lane < 16) u.p2.credu[w][lane] = csum;
    }
    __syncthreads();   // gs + credu ready

    // in-block compaction of this block's 16 critic values into cP/cR
    if (t < 16) {
        float cs = u.p2.credu[0][t] + u.p2.credu[1][t] +
                   u.p2.credu[2][t] + u.p2.credu[3][t];
        bool pr = (s[m0 + t] == pv[0]);
        unsigned long long mk = __ballot(pr);
        int np = __popcll(mk);
        int baseP = 0, baseR = 0;
        if (t == 0) {
            baseP = atomicAdd((int*)hdr + 129, np);
            baseR = atomicAdd((int*)hdr + 130, 16 - np);
        }
        baseP = __shfl(baseP, 0);
        baseR = __shfl(baseR, 0);
        int offP = __popcll(mk & ((1ull << t) - 1ull));
        int offR = t - offP;
        if (pr) cP[baseP + offP] = cs; else cR[baseR + offR] = cs;
    }

    // ---------------- phase 2: g @ Wd + MSE (no barriers) -------------------
    float lsum = 0.f;
    f32x4 a2[4] = {};
#pragma unroll
    for (int it = 0; it < 32; ++it) {
        const int cb = it & 1, pass = it >> 3, kc = it & 7;
        const int ml = li;
        const int phys = (kc * 4 + q) ^ ml;
        bf16x8 af = __builtin_bit_cast(bf16x8, *(const us8*)&u.p2.gs[ml * 256 + phys * 8]);
#pragma unroll
        for (int j = 0; j < 4; j++) {
            bf16x8 bf = __builtin_bit_cast(bf16x8, gb[cb][j]);
            a2[j] = __builtin_amdgcn_mfma_f32_16x16x32_bf16(bf, af, a2[j], 0, 0, 0);
        }
        if (it + 2 < 32) {
            const int p2i = (it + 2) >> 3, k2 = (it + 2) & 7;
#pragma unroll
            for (int j = 0; j < 4; j++)
                gb[cb][j] = *(const us8*)(Wp + ((size_t)((p2i * 16 + w * 4 + j) * 8 + k2)) * 512);
        }
        if (kc == 7) {   // per-pass epilogue: rec vs X fp32 (L3-warm)
            const size_t rowoff = (size_t)(m0 + li) * NF;
#pragma unroll
            for (int j = 0; j < 4; j++) {
                const int colb = pass * 256 + wn + j * 16 + q * 4;
                float4 bd4 = *(const float4*)&bd[colb];
                float4 xr  = *(const float4*)&X[rowoff + colb];
                float d0 = a2[j][0] + bd4.x - xr.x;
                float d1 = a2[j][1] + bd4.y - xr.y;
                float d2 = a2[j][2] + bd4.z - xr.z;
                float d3 = a2[j][3] + bd4.w - xr.w;
                lsum += d0 * d0 + d1 * d1 + d2 * d2 + d3 * d3;
                a2[j] = (f32x4){0.f, 0.f, 0.f, 0.f};
            }
        }
    }
#pragma unroll
    for (int o = 32; o; o >>= 1) lsum += __shfl_down(lsum, o);
    if (lane == 0) u.p2.msred[w] = lsum;
    __syncthreads();
    if (t == 0)
        atomicAdd(&hdr[b & 63], u.p2.msred[0] + u.p2.msred[1] +
                                u.p2.msred[2] + u.p2.msred[3]);
}

// ---------------------------------------------------------------------------
// compacted pairwise L1 + fused finalize (last-ticket block writes d_out)
// grid (16 j-chunks x 32 i-chunks of 512)
// ---------------------------------------------------------------------------
__global__ __launch_bounds__(256) void pair_fin_kernel(
    const float* __restrict__ cP, const float* __restrict__ cR,
    float* __restrict__ hdr, float* __restrict__ out) {
    __shared__ float sj[1024];
    __shared__ float red[256];
    __shared__ int win;
    const int nP = ((const int*)hdr)[129];
    const int nR = ((const int*)hdr)[130];
    const int jb = blockIdx.x * 1024;
    int jn = nR - jb; if (jn < 0) jn = 0; if (jn > 1024) jn = 1024;
    float sum = 0.f;
    if (jn > 0 && blockIdx.y * 512 < nP) {
        for (int j = threadIdx.x; j < 1024; j += 256)
            sj[j] = (jb + j < nR) ? cR[jb + j] : 0.f;
        __syncthreads();
        const int a0 = blockIdx.y * 512 + threadIdx.x, a1 = a0 + 256;
        const float ca0 = (a0 < nP) ? cP[a0] : 0.f;
        const float ca1 = (a1 < nP) ? cP[a1] : 0.f;
        float s0 = 0.f, s1 = 0.f;
#pragma unroll 8
        for (int j4 = 0; j4 < 256; j4++) {
            float4 v = *(const float4*)&sj[j4 * 4];
            s0 += fabsf(ca0 - v.x) + fabsf(ca0 - v.y) + fabsf(ca0 - v.z) + fabsf(ca0 - v.w);
            s1 += fabsf(ca1 - v.x) + fabsf(ca1 - v.y) + fabsf(ca1 - v.z) + fabsf(ca1 - v.w);
        }
        float pad = (float)(1024 - jn);
        s0 -= pad * fabsf(ca0);
        s1 -= pad * fabsf(ca1);
        if (a0 >= nP) s0 = 0.f;
        if (a1 >= nP) s1 = 0.f;
        sum = s0 + s1;
#pragma unroll
        for (int o = 32; o; o >>= 1) sum += __shfl_down(sum, o);
        if ((threadIdx.x & 63) == 0 && sum != 0.f)
            atomicAdd(&hdr[64 + ((blockIdx.y * 16 + blockIdx.x) & 63)], sum);
    }
    __threadfence();
    __syncthreads();
    if (threadIdx.x == 0)
        win = (atomicAdd((int*)(hdr + 128), 1) == 16 * 32 - 1) ? 1 : 0;
    __syncthreads();
    if (win) {
        float v = (threadIdx.x < 128) ? atomicAdd(&hdr[threadIdx.x], 0.f) : 0.f;
        red[threadIdx.x] = v;
        __syncthreads();
        if (threadIdx.x == 0) {
            float ms = 0.f, ps = 0.f;
            for (int i = 0; i < 64; i++) { ms += red[i]; ps += red[64 + i]; }
            int np = atomicAdd((int*)(hdr + 129), 0);
            out[0] = ms / (float)((size_t)NR * NF);
            out[1] = (float)NR;
            out[2] = ps / (float)np;
            out[3] = (float)np;
        }
    }
}

extern "C" void kernel_launch(void* const* d_in, const int* in_sizes, int n_in,
                              void* d_out, int out_size, void* d_ws, size_t ws_size,
                              hipStream_t stream) {
    const float* X  = (const float*)d_in[0];
    const float* We = (const float*)d_in[1];
    const float* be = (const float*)d_in[2];
    const float* Wd = (const float*)d_in[3];
    const float* bd = (const float*)d_in[4];
    const float* Wc = (const float*)d_in[5];
    // bc (d_in[6]) omitted: cancels in |c_i - c_j|
    const int*   s  = (const int*)d_in[7];
    const int*   pv = (const int*)d_in[8];

    char* ws = (char*)d_ws;
    float* hdr = (float*)ws;                                     // 192 f
    float* cP  = (float*)(ws + 1024);                            // 64 KB
    float* cR  = (float*)(ws + 1024 + 65536);                    // 64 KB
    unsigned short* Wepk = (unsigned short*)(ws + 1024 + 2 * 65536);  // 512 KB
    unsigned short* Wdpk = Wepk + (size_t)NH * NF;                    // 512 KB

    prep_kernel<<<32, 256, 0, stream>>>(We, Wd, Wepk, Wdpk, hdr);
    fused_kernel<<<1024, 256, 0, stream>>>(X, Wepk, Wdpk, be, bd, Wc, s, pv, cP, cR, hdr);
    pair_fin_kernel<<<dim3(16, 32), 256, 0, stream>>>(cP, cR, hdr, (float*)d_out);
}

// Round 5
// 208.789 us; speedup vs baseline: 1.0473x; 1.0269x over previous
//
#include <hip/hip_runtime.h>
#include <hip/hip_bf16.h>
#include <cstdint>

// Problem constants (reference: N=16384, F=1024, H=256)
#define NR 16384
#define NF 1024
#define NH 256

typedef __bf16 bf16x8 __attribute__((ext_vector_type(8)));
typedef float f32x4 __attribute__((ext_vector_type(4)));
typedef unsigned short us8 __attribute__((ext_vector_type(8)));

static __device__ __forceinline__ unsigned short f2bf(float f) {
    unsigned u = __float_as_uint(f);
    u += 0x7FFFu + ((u >> 16) & 1u);   // RNE
    return (unsigned short)(u >> 16);
}

// Fragment-major packed weights (1 KB per cell = 64 lanes x 16 B):
//   Wepk[nb=16][kc=32][lane=q*16+n][e=8] = bf16(We[kc*32+q*8+e][nb*16+n])
//   Wdpk[nb=64][kc= 8][lane=q*16+n][e=8] = bf16(Wd[kc*32+q*8+e][nb*16+n])
// hdr: [0..63] mse cells, [64..127] pair cells, [128] pair ticket,
//      [129] nP (int), [130] nR (int)

// ---------------------------------------------------------------------------
// prep (R4 rewrite): COALESCED packing. 256 blocks x 256 thr.
// R4 counters implied old prep (32 blocks, 1-4KB-strided scalar loads) was a
// large latency-bound slice of the ~126us non-fused time.
// Thread c owns one weight COLUMN; reads 8 consecutive k-rows. Each global
// load instruction = 256 threads x 4B consecutive = fully coalesced.
//   b <  128: We k-group k0=b   (rows 8b..8b+7), col c = t      (256 cols)
//   b >= 128: Wd k-group k0=idx>>2 (8 rows), col c = (idx&3)*256 + t
// ---------------------------------------------------------------------------
__global__ __launch_bounds__(256) void prep_kernel(
    const float* __restrict__ We, const float* __restrict__ Wd,
    unsigned short* __restrict__ Wepk, unsigned short* __restrict__ Wdpk,
    float* __restrict__ hdr) {
    const int b = blockIdx.x, t = threadIdx.x;
    if (b == 0 && t < 192) hdr[t] = 0.f;
    if (b < 128) {
        const int k0 = b, c = t;                       // k rows 8*k0..8*k0+7
        const int kc = k0 >> 2, q = k0 & 3, nb = c >> 4, li = c & 15;
        us8 v;
#pragma unroll
        for (int e = 0; e < 8; e++)
            v[e] = f2bf(We[(size_t)(k0 * 8 + e) * NH + c]);
        *(us8*)&Wepk[((size_t)(nb * 32 + kc)) * 512 + (q * 16 + li) * 8] = v;
    } else {
        const int idx = b - 128;
        const int k0 = idx >> 2, c = (idx & 3) * 256 + t;
        const int kc = k0 >> 2, q = k0 & 3, nb = c >> 4, li = c & 15;
        us8 v;
#pragma unroll
        for (int e = 0; e < 8; e++)
            v[e] = f2bf(Wd[(size_t)(k0 * 8 + e) * NF + c]);
        *(us8*)&Wdpk[((size_t)(nb * 8 + kc)) * 512 + (q * 16 + li) * 8] = v;
    }
}

// ---------------------------------------------------------------------------
// FUSED: grid 1024 x 256 thr (4 waves), 16 m-rows/block, 32 KB LDS.
// R4 changes: (a) stage rewritten for dense per-instruction coalescing
// (R4 counters: FETCH 69MB at 780 GB/s == kernel time; old stage had lanes
// 256B apart = 64 lines/instr, 16B used each). Wave owns 4 rows; lanes read
// lane*32B contiguous. (b) B-prefetch depth 2->4 in both GEMM phases
// (distance-2 ~100cyc < L2 ~200cyc => per-iteration vmcnt stall).
//  phase 0: stage own X strip (16x1024) -> LDS bf16, granule^row swizzle
//  phase 1: g = X @ We + be (A from LDS, B = Wepk 4-deep prefetch)
//  epilogue: critic c per row -> in-block compaction into cP/cR
//  phase 2: rec = g @ Wd + bd (A = gs LDS, B = Wdpk 4-deep prefetch); MSE
// Per-row K accumulation order identical to baseline -> same numerics.
// ---------------------------------------------------------------------------
__global__ __launch_bounds__(256) void fused_kernel(
    const float* __restrict__ X,
    const unsigned short* __restrict__ Wepk, const unsigned short* __restrict__ Wdpk,
    const float* __restrict__ be, const float* __restrict__ bd,
    const float* __restrict__ Wc, const int* __restrict__ s, const int* __restrict__ pv,
    float* __restrict__ cP, float* __restrict__ cR, float* __restrict__ hdr) {
    __shared__ union {
        unsigned short xa[16 * 1024];   // 32 KB: bf16 X tile (phases 0/1)
        struct {
            unsigned short gs[16 * 256]; // 8 KB: g tile (phase 2)
            float credu[4][16];
            float msred[4];
        } p2;
    } u;
    const int t = threadIdx.x;
    const int b = blockIdx.x, m0 = b * 16;
    const int w = t >> 6, lane = t & 63, q = lane >> 4, li = lane & 15;
    const int wn = w * 64;    // wave n-slice [wn, wn+64)

    // ---------------- phase 0: stage X tile (coalesced, swizzled) ----------
    // wave w -> rows 4w..4w+3; per row, lane reads 8 consecutive floats at
    // lane*32B; per (row,p) half-row the wave covers 2KB densely.
    {
#pragma unroll
        for (int rr = 0; rr < 4; ++rr) {
            const int r = w * 4 + rr;
            const float* xrow = X + (size_t)(m0 + r) * NF;
#pragma unroll
            for (int p = 0; p < 2; ++p) {
                float4 lo = *(const float4*)(xrow + p * 512 + lane * 8);
                float4 hi = *(const float4*)(xrow + p * 512 + lane * 8 + 4);
                us8 v;
                v[0] = f2bf(lo.x); v[1] = f2bf(lo.y); v[2] = f2bf(lo.z); v[3] = f2bf(lo.w);
                v[4] = f2bf(hi.x); v[5] = f2bf(hi.y); v[6] = f2bf(hi.z); v[7] = f2bf(hi.w);
                const int ch = p * 64 + lane;          // k-chunk 0..127
                *(us8*)&u.xa[r * 1024 + ((ch ^ r) & 127) * 8] = v;
            }
        }
    }
    __syncthreads();

    // ---------------- phase 1: X @ We (4-deep B prefetch, no barriers) ------
    const unsigned short* Bp[4];
#pragma unroll
    for (int j = 0; j < 4; j++)
        Bp[j] = Wepk + ((size_t)(w * 4 + j) * 32) * 512 + lane * 8;

    us8 fb[4][4];
#pragma unroll
    for (int z = 0; z < 4; ++z)
#pragma unroll
        for (int j = 0; j < 4; j++) fb[z][j] = *(const us8*)(Bp[j] + z * 512);

    f32x4 acc[4] = {};
#pragma unroll
    for (int kc = 0; kc < 32; ++kc) {
        const int cb = kc & 3;
        const int chl = kc * 4 + q;                       // 0..127
        const int ph0 = (chl ^ li) & 127;
        bf16x8 a0 = __builtin_bit_cast(bf16x8, *(const us8*)&u.xa[li * 1024 + ph0 * 8]);
#pragma unroll
        for (int j = 0; j < 4; j++) {
            bf16x8 bf = __builtin_bit_cast(bf16x8, fb[cb][j]);
            acc[j] = __builtin_amdgcn_mfma_f32_16x16x32_bf16(bf, a0, acc[j], 0, 0, 0);
        }
        if (kc + 4 < 32) {
#pragma unroll
            for (int j = 0; j < 4; j++) fb[cb][j] = *(const us8*)(Bp[j] + (kc + 4) * 512);
        }
    }
    __syncthreads();   // all waves done reading xa; p2 region writable

    // phase-2 B prefetch (global, independent) issued before epilogue
    const unsigned short* Wp = Wdpk + lane * 8;
    us8 gb[4][4];
#pragma unroll
    for (int z = 0; z < 4; ++z)
#pragma unroll
        for (int j = 0; j < 4; j++)
            gb[z][j] = *(const us8*)(Wp + ((size_t)((w * 4 + j) * 8 + z)) * 512);

    // epilogue: g -> swizzled gs + fused critic (single 16-row m-frag)
    {
        float csum = 0.f;
        const int ml = li;
#pragma unroll
        for (int j = 0; j < 4; j++) {
            const int colb = wn + j * 16 + q * 4;
            float4 be4 = *(const float4*)&be[colb];
            float4 wc4 = *(const float4*)&Wc[colb];
            float v0 = acc[j][0] + be4.x;
            float v1 = acc[j][1] + be4.y;
            float v2 = acc[j][2] + be4.z;
            float v3 = acc[j][3] + be4.w;
            csum += v0 * wc4.x + v1 * wc4.y + v2 * wc4.z + v3 * wc4.w;
            ushort4 st = { f2bf(v0), f2bf(v1), f2bf(v2), f2bf(v3) };
            const int phys = (colb >> 3) ^ ml;
            *(ushort4*)&u.p2.gs[ml * 256 + phys * 8 + (q & 1) * 4] = st;
        }
        csum += __shfl_down(csum, 32);
        csum += __shfl_down(csum, 16);
        if (lane < 16) u.p2.credu[w][lane] = csum;
    }
    __syncthreads();   // gs + credu ready

    // in-block compaction of this block's 16 critic values into cP/cR
    if (t < 16) {
        float cs = u.p2.credu[0][t] + u.p2.credu[1][t] +
                   u.p2.credu[2][t] + u.p2.credu[3][t];
        bool pr = (s[m0 + t] == pv[0]);
        unsigned long long mk = __ballot(pr);
        int np = __popcll(mk);
        int baseP = 0, baseR = 0;
        if (t == 0) {
            baseP = atomicAdd((int*)hdr + 129, np);
            baseR = atomicAdd((int*)hdr + 130, 16 - np);
        }
        baseP = __shfl(baseP, 0);
        baseR = __shfl(baseR, 0);
        int offP = __popcll(mk & ((1ull << t) - 1ull));
        int offR = t - offP;
        if (pr) cP[baseP + offP] = cs; else cR[baseR + offR] = cs;
    }

    // ---------------- phase 2: g @ Wd + MSE (no barriers) -------------------
    float lsum = 0.f;
    f32x4 a2[4] = {};
#pragma unroll
    for (int it = 0; it < 32; ++it) {
        const int cb = it & 3, pass = it >> 3, kc = it & 7;
        const int ml = li;
        const int phys = (kc * 4 + q) ^ ml;
        bf16x8 af = __builtin_bit_cast(bf16x8, *(const us8*)&u.p2.gs[ml * 256 + phys * 8]);
#pragma unroll
        for (int j = 0; j < 4; j++) {
            bf16x8 bf = __builtin_bit_cast(bf16x8, gb[cb][j]);
            a2[j] = __builtin_amdgcn_mfma_f32_16x16x32_bf16(bf, af, a2[j], 0, 0, 0);
        }
        if (it + 4 < 32) {
            const int p2i = (it + 4) >> 3, k2 = (it + 4) & 7;
#pragma unroll
            for (int j = 0; j < 4; j++)
                gb[cb][j] = *(const us8*)(Wp + ((size_t)((p2i * 16 + w * 4 + j) * 8 + k2)) * 512);
        }
        if (kc == 7) {   // per-pass epilogue: rec vs X fp32 (L3-warm)
            const size_t rowoff = (size_t)(m0 + li) * NF;
#pragma unroll
            for (int j = 0; j < 4; j++) {
                const int colb = pass * 256 + wn + j * 16 + q * 4;
                float4 bd4 = *(const float4*)&bd[colb];
                float4 xr  = *(const float4*)&X[rowoff + colb];
                float d0 = a2[j][0] + bd4.x - xr.x;
                float d1 = a2[j][1] + bd4.y - xr.y;
                float d2 = a2[j][2] + bd4.z - xr.z;
                float d3 = a2[j][3] + bd4.w - xr.w;
                lsum += d0 * d0 + d1 * d1 + d2 * d2 + d3 * d3;
                a2[j] = (f32x4){0.f, 0.f, 0.f, 0.f};
            }
        }
    }
#pragma unroll
    for (int o = 32; o; o >>= 1) lsum += __shfl_down(lsum, o);
    if (lane == 0) u.p2.msred[w] = lsum;
    __syncthreads();
    if (t == 0)
        atomicAdd(&hdr[b & 63], u.p2.msred[0] + u.p2.msred[1] +
                                u.p2.msred[2] + u.p2.msred[3]);
}

// ---------------------------------------------------------------------------
// compacted pairwise L1 + fused finalize (last-ticket block writes d_out)
// grid (16 j-chunks x 32 i-chunks of 512)
// ---------------------------------------------------------------------------
__global__ __launch_bounds__(256) void pair_fin_kernel(
    const float* __restrict__ cP, const float* __restrict__ cR,
    float* __restrict__ hdr, float* __restrict__ out) {
    __shared__ float sj[1024];
    __shared__ float red[256];
    __shared__ int win;
    const int nP = ((const int*)hdr)[129];
    const int nR = ((const int*)hdr)[130];
    const int jb = blockIdx.x * 1024;
    int jn = nR - jb; if (jn < 0) jn = 0; if (jn > 1024) jn = 1024;
    float sum = 0.f;
    if (jn > 0 && blockIdx.y * 512 < nP) {
        for (int j = threadIdx.x; j < 1024; j += 256)
            sj[j] = (jb + j < nR) ? cR[jb + j] : 0.f;
        __syncthreads();
        const int a0 = blockIdx.y * 512 + threadIdx.x, a1 = a0 + 256;
        const float ca0 = (a0 < nP) ? cP[a0] : 0.f;
        const float ca1 = (a1 < nP) ? cP[a1] : 0.f;
        float s0 = 0.f, s1 = 0.f;
#pragma unroll 8
        for (int j4 = 0; j4 < 256; j4++) {
            float4 v = *(const float4*)&sj[j4 * 4];
            s0 += fabsf(ca0 - v.x) + fabsf(ca0 - v.y) + fabsf(ca0 - v.z) + fabsf(ca0 - v.w);
            s1 += fabsf(ca1 - v.x) + fabsf(ca1 - v.y) + fabsf(ca1 - v.z) + fabsf(ca1 - v.w);
        }
        float pad = (float)(1024 - jn);
        s0 -= pad * fabsf(ca0);
        s1 -= pad * fabsf(ca1);
        if (a0 >= nP) s0 = 0.f;
        if (a1 >= nP) s1 = 0.f;
        sum = s0 + s1;
#pragma unroll
        for (int o = 32; o; o >>= 1) sum += __shfl_down(sum, o);
        if ((threadIdx.x & 63) == 0 && sum != 0.f)
            atomicAdd(&hdr[64 + ((blockIdx.y * 16 + blockIdx.x) & 63)], sum);
    }
    __threadfence();
    __syncthreads();
    if (threadIdx.x == 0)
        win = (atomicAdd((int*)(hdr + 128), 1) == 16 * 32 - 1) ? 1 : 0;
    __syncthreads();
    if (win) {
        float v = (threadIdx.x < 128) ? atomicAdd(&hdr[threadIdx.x], 0.f) : 0.f;
        red[threadIdx.x] = v;
        __syncthreads();
        if (threadIdx.x == 0) {
            float ms = 0.f, ps = 0.f;
            for (int i = 0; i < 64; i++) { ms += red[i]; ps += red[64 + i]; }
            int np = atomicAdd((int*)(hdr + 129), 0);
            out[0] = ms / (float)((size_t)NR * NF);
            out[1] = (float)NR;
            out[2] = ps / (float)np;
            out[3] = (float)np;
        }
    }
}

extern "C" void kernel_launch(void* const* d_in, const int* in_sizes, int n_in,
                              void* d_out, int out_size, void* d_ws, size_t ws_size,
                              hipStream_t stream) {
    const float* X  = (const float*)d_in[0];
    const float* We = (const float*)d_in[1];
    const float* be = (const float*)d_in[2];
    const float* Wd = (const float*)d_in[3];
    const float* bd = (const float*)d_in[4];
    const float* Wc = (const float*)d_in[5];
    // bc (d_in[6]) omitted: cancels in |c_i - c_j|
    const int*   s  = (const int*)d_in[7];
    const int*   pv = (const int*)d_in[8];

    char* ws = (char*)d_ws;
    float* hdr = (float*)ws;                                     // 192 f
    float* cP  = (float*)(ws + 1024);                            // 64 KB
    float* cR  = (float*)(ws + 1024 + 65536);                    // 64 KB
    unsigned short* Wepk = (unsigned short*)(ws + 1024 + 2 * 65536);  // 512 KB
    unsigned short* Wdpk = Wepk + (size_t)NH * NF;                    // 512 KB

    prep_kernel<<<256, 256, 0, stream>>>(We, Wd, Wepk, Wdpk, hdr);
    fused_kernel<<<1024, 256, 0, stream>>>(X, Wepk, Wdpk, be, bd, Wc, s, pv, cP, cR, hdr);
    pair_fin_kernel<<<dim3(16, 32), 256, 0, stream>>>(cP, cR, hdr, (float*)d_out);
}

// Round 9
// 182.655 us; speedup vs baseline: 1.1972x; 1.1431x over previous
//
#include <hip/hip_runtime.h>
#include <hip/hip_bf16.h>
#include <cstdint>

// Problem constants (reference: N=16384, F=1024, H=256)
#define NR 16384
#define NF 1024
#define NH 256

typedef __bf16 bf16x8 __attribute__((ext_vector_type(8)));
typedef float f32x4 __attribute__((ext_vector_type(4)));
typedef unsigned short us8 __attribute__((ext_vector_type(8)));

static __device__ __forceinline__ unsigned short f2bf(float f) {
    unsigned u = __float_as_uint(f);
    u += 0x7FFFu + ((u >> 16) & 1u);   // RNE
    return (unsigned short)(u >> 16);
}

// Fragment-major packed weights (1 KB per cell = 64 lanes x 16 B):
//   Wepk[nb=16][kc=32][lane=q*16+n][e=8] = bf16(We[kc*32+q*8+e][nb*16+n])
//   Wdpk[nb=64][kc= 8][lane=q*16+n][e=8] = bf16(Wd[kc*32+q*8+e][nb*16+n])
// hdr: [0..63] mse cells, [64..127] pair cells, [128] pair ticket,
//      [129] nP (int), [130] nR (int)

// ---------------------------------------------------------------------------
// prep: coalesced packing (R5 version, unchanged). 256 blocks x 256 thr.
// ---------------------------------------------------------------------------
__global__ __launch_bounds__(256) void prep_kernel(
    const float* __restrict__ We, const float* __restrict__ Wd,
    unsigned short* __restrict__ Wepk, unsigned short* __restrict__ Wdpk,
    float* __restrict__ hdr) {
    const int b = blockIdx.x, t = threadIdx.x;
    if (b == 0 && t < 192) hdr[t] = 0.f;
    if (b < 128) {
        const int k0 = b, c = t;                       // k rows 8*k0..8*k0+7
        const int kc = k0 >> 2, q = k0 & 3, nb = c >> 4, li = c & 15;
        us8 v;
#pragma unroll
        for (int e = 0; e < 8; e++)
            v[e] = f2bf(We[(size_t)(k0 * 8 + e) * NH + c]);
        *(us8*)&Wepk[((size_t)(nb * 32 + kc)) * 512 + (q * 16 + li) * 8] = v;
    } else {
        const int idx = b - 128;
        const int k0 = idx >> 2, c = (idx & 3) * 256 + t;
        const int kc = k0 >> 2, q = k0 & 3, nb = c >> 4, li = c & 15;
        us8 v;
#pragma unroll
        for (int e = 0; e < 8; e++)
            v[e] = f2bf(Wd[(size_t)(k0 * 8 + e) * NF + c]);
        *(us8*)&Wdpk[((size_t)(nb * 8 + kc)) * 512 + (q * 16 + li) * 8] = v;
    }
}

// ---------------------------------------------------------------------------
// FUSED (R5 design, resubmitted after infra failures): grid 256 x 512 thr
// (8 waves), 64 m-rows/block.
// THEORY: R3-R5 fused time (80-88us) invariant to staging/occupancy because
// every block streams ALL 1MB packed weights => 16384/M MB of L2/L3 traffic.
// M=16 -> 1GB; this kernel: M=64 -> 256MB (4x cut). Wave owns a 32-col
// n-slice in phase 1 (disjoint B reads). X staged in 4 quarters of 64x256
// (32KB LDS) with T14 issue-early/write-late reg prefetch. B prefetch depth
// 8 (p1) / 4 (p2) to cover L3 latency (X streaming evicts weights from L2).
//  phase 1: g = X @ We (4 quarters; A from LDS, B = Wepk 8-deep)
//  epilogue: g -> swizzled gs + critic partials -> compaction into cP/cR
//  phase 2: rec = g @ Wd in 2 passes of 512 cols; MSE vs X fp32 per pass
// ---------------------------------------------------------------------------
__global__ __launch_bounds__(512) void fused_kernel(
    const float* __restrict__ X,
    const unsigned short* __restrict__ Wepk, const unsigned short* __restrict__ Wdpk,
    const float* __restrict__ be, const float* __restrict__ bd,
    const float* __restrict__ Wc, const int* __restrict__ s, const int* __restrict__ pv,
    float* __restrict__ cP, float* __restrict__ cR, float* __restrict__ hdr) {
    __shared__ union {
        unsigned short xa[64 * 256];     // 32 KB: bf16 X quarter (phases 0/1)
        struct {
            unsigned short gs[64 * 256]; // 32 KB: g tile (phase 2)
            float credu[8][64];
            float msred[8];
        } p2;
    } u;
    const int t = threadIdx.x;
    const int b = blockIdx.x, m0 = b * 64;
    const int w = t >> 6, lane = t & 63, q = lane >> 4, li = lane & 15;

    // staging geometry: wave w stages rows w*8..w*8+7; one float4 per lane
    // covers a full 256-float row-quarter (1KB/instr, fully coalesced).
    const int srow = w * 8;
    const int sch = lane >> 1, shalf = lane & 1;   // chunk 0..31, half 0..1

    // ---------------- stage quarter 0 --------------------------------------
    {
#pragma unroll
        for (int rr = 0; rr < 8; ++rr) {
            const int r = srow + rr;
            float4 v4 = *(const float4*)(X + (size_t)(m0 + r) * NF + lane * 4);
            ushort4 st = { f2bf(v4.x), f2bf(v4.y), f2bf(v4.z), f2bf(v4.w) };
            const int phys = (sch ^ (r & 31)) & 31;
            *(ushort4*)&u.xa[r * 256 + phys * 8 + shalf * 4] = st;
        }
    }
    __syncthreads();

    // ---------------- phase 1: X @ We (8-deep B prefetch) -------------------
    const unsigned short* Bp[2];
#pragma unroll
    for (int j = 0; j < 2; j++)
        Bp[j] = Wepk + ((size_t)(w * 2 + j) * 32) * 512 + lane * 8;

    us8 fb[8][2];
#pragma unroll
    for (int z = 0; z < 8; ++z)
#pragma unroll
        for (int j = 0; j < 2; j++) fb[z][j] = *(const us8*)(Bp[j] + z * 512);

    f32x4 acc[4][2] = {};
    float4 xn[8];

#pragma unroll
    for (int ks = 0; ks < 4; ++ks) {
        // T14 issue-early: next quarter's X loads, hidden under this
        // quarter's MFMA work.
        if (ks < 3) {
#pragma unroll
            for (int rr = 0; rr < 8; ++rr)
                xn[rr] = *(const float4*)(X + (size_t)(m0 + srow + rr) * NF +
                                          (ks + 1) * 256 + lane * 4);
        }
#pragma unroll
        for (int kcl = 0; kcl < 8; ++kcl) {
            const int kcg = ks * 8 + kcl;
            const int cb = kcg & 7;
            bf16x8 a[4];
#pragma unroll
            for (int mi = 0; mi < 4; ++mi) {
                const int r = mi * 16 + li;
                const int phys = ((kcl * 4 + q) ^ (r & 31)) & 31;
                a[mi] = __builtin_bit_cast(bf16x8, *(const us8*)&u.xa[r * 256 + phys * 8]);
            }
#pragma unroll
            for (int j = 0; j < 2; ++j) {
                bf16x8 bf = __builtin_bit_cast(bf16x8, fb[cb][j]);
#pragma unroll
                for (int mi = 0; mi < 4; ++mi)
                    acc[mi][j] = __builtin_amdgcn_mfma_f32_16x16x32_bf16(bf, a[mi], acc[mi][j], 0, 0, 0);
            }
            if (kcg + 8 < 32) {
#pragma unroll
                for (int j = 0; j < 2; j++) fb[cb][j] = *(const us8*)(Bp[j] + (kcg + 8) * 512);
            }
        }
        __syncthreads();          // all waves done reading this quarter
        if (ks < 3) {             // T14 write-late: regs -> LDS, re-barrier
#pragma unroll
            for (int rr = 0; rr < 8; ++rr) {
                const int r = srow + rr;
                ushort4 st = { f2bf(xn[rr].x), f2bf(xn[rr].y),
                               f2bf(xn[rr].z), f2bf(xn[rr].w) };
                const int phys = (sch ^ (r & 31)) & 31;
                *(ushort4*)&u.xa[r * 256 + phys * 8 + shalf * 4] = st;
            }
            __syncthreads();
        }
    }

    // epilogue: g -> swizzled gs + critic partials (wave n-slice = 32 cols)
#pragma unroll
    for (int mi = 0; mi < 4; ++mi) {
        float csum = 0.f;
        const int ml = mi * 16 + li;
#pragma unroll
        for (int j = 0; j < 2; ++j) {
            const int colb = w * 32 + j * 16 + q * 4;
            float4 be4 = *(const float4*)&be[colb];
            float4 wc4 = *(const float4*)&Wc[colb];
            float v0 = acc[mi][j][0] + be4.x;
            float v1 = acc[mi][j][1] + be4.y;
            float v2 = acc[mi][j][2] + be4.z;
            float v3 = acc[mi][j][3] + be4.w;
            csum += v0 * wc4.x + v1 * wc4.y + v2 * wc4.z + v3 * wc4.w;
            ushort4 st = { f2bf(v0), f2bf(v1), f2bf(v2), f2bf(v3) };
            const int ch = colb >> 3;
            const int phys = (ch ^ (ml & 31)) & 31;
            *(ushort4*)&u.p2.gs[ml * 256 + phys * 8 + (q & 1) * 4] = st;
        }
        csum += __shfl_down(csum, 32);
        csum += __shfl_down(csum, 16);
        if (lane < 16) u.p2.credu[w][mi * 16 + lane] = csum;
    }
    __syncthreads();   // gs + credu ready

    // in-block compaction of this block's 64 critic values (wave 0)
    if (t < 64) {
        float cs = 0.f;
#pragma unroll
        for (int ww = 0; ww < 8; ++ww) cs += u.p2.credu[ww][t];
        bool pr = (s[m0 + t] == pv[0]);
        unsigned long long mk = __ballot(pr);
        int np = __popcll(mk);
        int baseP = 0, baseR = 0;
        if (t == 0) {
            baseP = atomicAdd((int*)hdr + 129, np);
            baseR = atomicAdd((int*)hdr + 130, 64 - np);
        }
        baseP = __shfl(baseP, 0);
        baseR = __shfl(baseR, 0);
        int offP = __popcll(mk & ((1ull << t) - 1ull));
        int offR = t - offP;
        if (pr) cP[baseP + offP] = cs; else cR[baseR + offR] = cs;
    }

    // ---------------- phase 2: g @ Wd + MSE (2 passes x 512 cols) -----------
    float lsum = 0.f;
    const unsigned short* Wp = Wdpk + lane * 8;
#pragma unroll
    for (int pass = 0; pass < 2; ++pass) {
        const int nb0 = pass * 32 + w * 4;     // 4 n-blocks of 16 per wave
        us8 gb[4][4];
#pragma unroll
        for (int z = 0; z < 4; ++z)
#pragma unroll
            for (int j = 0; j < 4; ++j)
                gb[z][j] = *(const us8*)(Wp + ((size_t)((nb0 + j) * 8 + z)) * 512);
        f32x4 a2[4][4] = {};
#pragma unroll
        for (int kc = 0; kc < 8; ++kc) {
            const int cb = kc & 3;
            bf16x8 af[4];
#pragma unroll
            for (int mi = 0; mi < 4; ++mi) {
                const int ml = mi * 16 + li;
                const int phys = ((kc * 4 + q) ^ (ml & 31)) & 31;
                af[mi] = __builtin_bit_cast(bf16x8, *(const us8*)&u.p2.gs[ml * 256 + phys * 8]);
            }
#pragma unroll
            for (int j = 0; j < 4; ++j) {
                bf16x8 bf = __builtin_bit_cast(bf16x8, gb[cb][j]);
#pragma unroll
                for (int mi = 0; mi < 4; ++mi)
                    a2[mi][j] = __builtin_amdgcn_mfma_f32_16x16x32_bf16(bf, af[mi], a2[mi][j], 0, 0, 0);
            }
            if (kc + 4 < 8) {
#pragma unroll
                for (int j = 0; j < 4; ++j)
                    gb[cb][j] = *(const us8*)(Wp + ((size_t)((nb0 + j) * 8 + kc + 4)) * 512);
            }
        }
        // MSE epilogue for this 512-col pass (X re-read: L3-warm)
#pragma unroll
        for (int mi = 0; mi < 4; ++mi) {
            const size_t rowoff = (size_t)(m0 + mi * 16 + li) * NF;
#pragma unroll
            for (int j = 0; j < 4; ++j) {
                const int colb = pass * 512 + w * 64 + j * 16 + q * 4;
                float4 bd4 = *(const float4*)&bd[colb];
                float4 xr  = *(const float4*)&X[rowoff + colb];
                float d0 = a2[mi][j][0] + bd4.x - xr.x;
                float d1 = a2[mi][j][1] + bd4.y - xr.y;
                float d2 = a2[mi][j][2] + bd4.z - xr.z;
                float d3 = a2[mi][j][3] + bd4.w - xr.w;
                lsum += d0 * d0 + d1 * d1 + d2 * d2 + d3 * d3;
            }
        }
    }
#pragma unroll
    for (int o = 32; o; o >>= 1) lsum += __shfl_down(lsum, o);
    if (lane == 0) u.p2.msred[w] = lsum;
    __syncthreads();
    if (t == 0) {
        float ms = 0.f;
#pragma unroll
        for (int ww = 0; ww < 8; ++ww) ms += u.p2.msred[ww];
        atomicAdd(&hdr[b & 63], ms);
    }
}

// ---------------------------------------------------------------------------
// compacted pairwise L1 + fused finalize (last-ticket block writes d_out)
// grid (16 j-chunks x 32 i-chunks of 512)
// ---------------------------------------------------------------------------
__global__ __launch_bounds__(256) void pair_fin_kernel(
    const float* __restrict__ cP, const float* __restrict__ cR,
    float* __restrict__ hdr, float* __restrict__ out) {
    __shared__ float sj[1024];
    __shared__ float red[256];
    __shared__ int win;
    const int nP = ((const int*)hdr)[129];
    const int nR = ((const int*)hdr)[130];
    const int jb = blockIdx.x * 1024;
    int jn = nR - jb; if (jn < 0) jn = 0; if (jn > 1024) jn = 1024;
    float sum = 0.f;
    if (jn > 0 && blockIdx.y * 512 < nP) {
        for (int j = threadIdx.x; j < 1024; j += 256)
            sj[j] = (jb + j < nR) ? cR[jb + j] : 0.f;
        __syncthreads();
        const int a0 = blockIdx.y * 512 + threadIdx.x, a1 = a0 + 256;
        const float ca0 = (a0 < nP) ? cP[a0] : 0.f;
        const float ca1 = (a1 < nP) ? cP[a1] : 0.f;
        float s0 = 0.f, s1 = 0.f;
#pragma unroll 8
        for (int j4 = 0; j4 < 256; j4++) {
            float4 v = *(const float4*)&sj[j4 * 4];
            s0 += fabsf(ca0 - v.x) + fabsf(ca0 - v.y) + fabsf(ca0 - v.z) + fabsf(ca0 - v.w);
            s1 += fabsf(ca1 - v.x) + fabsf(ca1 - v.y) + fabsf(ca1 - v.z) + fabsf(ca1 - v.w);
        }
        float pad = (float)(1024 - jn);
        s0 -= pad * fabsf(ca0);
        s1 -= pad * fabsf(ca1);
        if (a0 >= nP) s0 = 0.f;
        if (a1 >= nP) s1 = 0.f;
        sum = s0 + s1;
#pragma unroll
        for (int o = 32; o; o >>= 1) sum += __shfl_down(sum, o);
        if ((threadIdx.x & 63) == 0 && sum != 0.f)
            atomicAdd(&hdr[64 + ((blockIdx.y * 16 + blockIdx.x) & 63)], sum);
    }
    __threadfence();
    __syncthreads();
    if (threadIdx.x == 0)
        win = (atomicAdd((int*)(hdr + 128), 1) == 16 * 32 - 1) ? 1 : 0;
    __syncthreads();
    if (win) {
        float v = (threadIdx.x < 128) ? atomicAdd(&hdr[threadIdx.x], 0.f) : 0.f;
        red[threadIdx.x] = v;
        __syncthreads();
        if (threadIdx.x == 0) {
            float ms = 0.f, ps = 0.f;
            for (int i = 0; i < 64; i++) { ms += red[i]; ps += red[64 + i]; }
            int np = atomicAdd((int*)(hdr + 129), 0);
            out[0] = ms / (float)((size_t)NR * NF);
            out[1] = (float)NR;
            out[2] = ps / (float)np;
            out[3] = (float)np;
        }
    }
}

extern "C" void kernel_launch(void* const* d_in, const int* in_sizes, int n_in,
                              void* d_out, int out_size, void* d_ws, size_t ws_size,
                              hipStream_t stream) {
    const float* X  = (const float*)d_in[0];
    const float* We = (const float*)d_in[1];
    const float* be = (const float*)d_in[2];
    const float* Wd = (const float*)d_in[3];
    const float* bd = (const float*)d_in[4];
    const float* Wc = (const float*)d_in[5];
    // bc (d_in[6]) omitted: cancels in |c_i - c_j|
    const int*   s  = (const int*)d_in[7];
    const int*   pv = (const int*)d_in[8];

    char* ws = (char*)d_ws;
    float* hdr = (float*)ws;                                     // 192 f
    float* cP  = (float*)(ws + 1024);                            // 64 KB
    float* cR  = (float*)(ws + 1024 + 65536);                    // 64 KB
    unsigned short* Wepk = (unsigned short*)(ws + 1024 + 2 * 65536);  // 512 KB
    unsigned short* Wdpk = Wepk + (size_t)NH * NF;                    // 512 KB

    prep_kernel<<<256, 256, 0, stream>>>(We, Wd, Wepk, Wdpk, hdr);
    fused_kernel<<<256, 512, 0, stream>>>(X, Wepk, Wdpk, be, bd, Wc, s, pv, cP, cR, hdr);
    pair_fin_kernel<<<dim3(16, 32), 256, 0, stream>>>(cP, cR, hdr, (float*)d_out);
}